// Round 3
// baseline (2474.471 us; speedup 1.0000x reference)
//
#include <hip/hip_runtime.h>
#include <hip/hip_bf16.h>

#define NN 50000
#define EE 800000
#define DD 128

// ---------------- degree (guarded) ----------------
__global__ void k_deg(const int* __restrict__ ei, int* __restrict__ deg) {
    int e = blockIdx.x * 256 + threadIdx.x;
    if (e < EE) {
        int d = ei[EE + e];                       // dst row
        if (d >= 0 && d < NN) atomicAdd(&deg[d], 1);
    }
}

__global__ void k_dis(const int* __restrict__ deg, float* __restrict__ dis) {
    int i = blockIdx.x * 256 + threadIdx.x;
    if (i < NN) dis[i] = rsqrtf((float)deg[i] + 1.0f);  // +1 self loop; always >0
}

// ---------------- GEMM: OUT = IN @ W (+epilogue) ----------------
// MODE 0: OUT[r][:] = (IN@W)[r][:] * dis[r]          (conv pre-aggregation)
// MODE 1: OUT = relu(IN@W + bias)                    (mlp layers)
// IN [N][128] fp32, W [128][128] fp32 row-major (k,c), OUT [N][128] fp32.
// Tile: 64 rows x 128 cols per block, 256 threads, thread tile 4x8, BK=64 x2.
template<int MODE>
__global__ __launch_bounds__(256) void k_gemm(const float* __restrict__ IN,
                                              const float* __restrict__ Wg,
                                              const float* __restrict__ bias,
                                              const float* __restrict__ dis,
                                              float* __restrict__ OUT) {
    __shared__ float Alds[64][68];    // padded: stride 68 (2-way max on reads, free)
    __shared__ float Wlds[64][128];
    const int tid = threadIdx.x;
    const int tx = tid & 15;          // col group: cols tx*8 .. +8
    const int ty = tid >> 4;          // row group: rows ty*4 .. +4
    const int row0 = blockIdx.x * 64;

    float acc[4][8];
#pragma unroll
    for (int i = 0; i < 4; ++i)
#pragma unroll
        for (int j = 0; j < 8; ++j) acc[i][j] = 0.f;

    for (int kc = 0; kc < 2; ++kc) {
        // stage A chunk: 64 rows x 64 k
#pragma unroll
        for (int it = 0; it < 4; ++it) {
            int idx = it * 1024 + tid * 4;          // element id in 64x64
            int r = idx >> 6, k = idx & 63;
            int gr = row0 + r;
            float4 v = make_float4(0.f, 0.f, 0.f, 0.f);
            if (gr < NN) v = *(const float4*)&IN[gr * DD + kc * 64 + k];
            *(float4*)&Alds[r][k] = v;
        }
        // stage W chunk: 64 k x 128 c
#pragma unroll
        for (int it = 0; it < 8; ++it) {
            int idx = it * 1024 + tid * 4;          // element id in 64x128
            int k = idx >> 7, c = idx & 127;
            *(float4*)&Wlds[k][c] = *(const float4*)&Wg[(kc * 64 + k) * DD + c];
        }
        __syncthreads();

#pragma unroll 8
        for (int k = 0; k < 64; ++k) {
            float a0 = Alds[ty * 4 + 0][k];
            float a1 = Alds[ty * 4 + 1][k];
            float a2 = Alds[ty * 4 + 2][k];
            float a3 = Alds[ty * 4 + 3][k];
            float4 w0 = *(float4*)&Wlds[k][tx * 8];
            float4 w1 = *(float4*)&Wlds[k][tx * 8 + 4];
            float w[8] = {w0.x, w0.y, w0.z, w0.w, w1.x, w1.y, w1.z, w1.w};
#pragma unroll
            for (int j = 0; j < 8; ++j) {
                acc[0][j] = fmaf(a0, w[j], acc[0][j]);
                acc[1][j] = fmaf(a1, w[j], acc[1][j]);
                acc[2][j] = fmaf(a2, w[j], acc[2][j]);
                acc[3][j] = fmaf(a3, w[j], acc[3][j]);
            }
        }
        __syncthreads();
    }

    float bcol[8];
    if (MODE == 1) {
#pragma unroll
        for (int j = 0; j < 8; ++j) bcol[j] = bias[tx * 8 + j];
    }
#pragma unroll
    for (int i = 0; i < 4; ++i) {
        int r = row0 + ty * 4 + i;
        if (r >= NN) break;
        float scale = (MODE == 0) ? dis[r] : 1.f;
        float o[8];
#pragma unroll
        for (int j = 0; j < 8; ++j) {
            float v = acc[i][j];
            if (MODE == 0) v *= scale;
            else           v = fmaxf(v + bcol[j], 0.f);
            o[j] = v;
        }
        *(float4*)&OUT[r * DD + tx * 8]     = make_float4(o[0], o[1], o[2], o[3]);
        *(float4*)&OUT[r * DD + tx * 8 + 4] = make_float4(o[4], o[5], o[6], o[7]);
    }
}

// ---------------- edge scatter: A[dst] += HS[src] (guarded) ----------------
__global__ __launch_bounds__(256) void k_scatter(const int* __restrict__ ei,
                                                 const float* __restrict__ HS,
                                                 float* __restrict__ A) {
    int e = blockIdx.x * 4 + (threadIdx.x >> 6);
    if (e >= EE) return;
    int lane = threadIdx.x & 63;
    int s = ei[e];
    int d = ei[EE + e];
    if ((unsigned)s >= (unsigned)NN || (unsigned)d >= (unsigned)NN) return;
    float2 v = ((const float2*)(HS + (size_t)s * DD))[lane];
    float* dst = A + (size_t)d * DD + lane * 2;
    atomicAdd(dst,     v.x);
    atomicAdd(dst + 1, v.y);
}

// ---------------- finalize: A = dis*(A + HS) + b  (opt relu), + col stats ----
template<int RELU>
__global__ __launch_bounds__(128) void k_finalize(float* __restrict__ A,
                                                  const float* __restrict__ HS,
                                                  const float* __restrict__ dis,
                                                  const float* __restrict__ bias,
                                                  float* __restrict__ colsum,
                                                  float* __restrict__ colsumsq) {
    int d = threadIdx.x;
    int r0 = blockIdx.x * 128;
    float b = bias[d];
    float s = 0.f, sq = 0.f;
    for (int i = 0; i < 128; ++i) {
        int r = r0 + i;
        if (r >= NN) break;
        float v = dis[r] * (A[r * DD + d] + HS[r * DD + d]) + b;
        if (RELU) v = fmaxf(v, 0.f);
        A[r * DD + d] = v;
        s += v;
        sq += v * v;
    }
    atomicAdd(&colsum[d], s);
    atomicAdd(&colsumsq[d], sq);
}

// ---------------- BN apply in-place (+opt relu) ----------------
__global__ __launch_bounds__(256) void k_norm(float* __restrict__ Y,
                                              const float* __restrict__ colsum,
                                              const float* __restrict__ colsumsq,
                                              const float* __restrict__ gamma,
                                              const float* __restrict__ beta,
                                              int relu) {
    int i = blockIdx.x * 256 + threadIdx.x;
    if (i >= NN * DD) return;
    int d = i & (DD - 1);
    const float invn = 1.f / (float)NN;
    float mean = colsum[d] * invn;
    float var = colsumsq[d] * invn - mean * mean;
    float v = (Y[i] - mean) * rsqrtf(fmaxf(var, 0.f) + 1e-5f) * gamma[d] + beta[d];
    if (relu) v = fmaxf(v, 0.f);
    Y[i] = v;
}

// ---------------- head: out = sigmoid(H @ out_w + out_b) ----------------
__global__ __launch_bounds__(256) void k_head(const float* __restrict__ H,
                                              const float* __restrict__ ow,
                                              const float* __restrict__ ob,
                                              float* __restrict__ out) {
    int r = blockIdx.x * 4 + (threadIdx.x >> 6);
    if (r >= NN) return;
    int lane = threadIdx.x & 63;
    float2 h = ((const float2*)(H + (size_t)r * DD))[lane];
    float sum = h.x * ow[lane * 2] + h.y * ow[lane * 2 + 1];
#pragma unroll
    for (int off = 32; off > 0; off >>= 1) sum += __shfl_down(sum, off);
    if (lane == 0) {
        float z = sum + ob[0];
        out[r] = 1.f / (1.f + expf(-z));
    }
}

extern "C" void kernel_launch(void* const* d_in, const int* in_sizes, int n_in,
                              void* d_out, int out_size, void* d_ws, size_t ws_size,
                              hipStream_t stream) {
    const float* x      = (const float*)d_in[0];
    const int*   ei     = (const int*)d_in[1];
    const float* conv_w = (const float*)d_in[2];
    const float* conv_b = (const float*)d_in[3];
    const float* bn_g   = (const float*)d_in[4];
    const float* bn_b   = (const float*)d_in[5];
    const float* mlp_w  = (const float*)d_in[6];
    const float* mlp_b  = (const float*)d_in[7];
    const float* out_w  = (const float*)d_in[8];
    const float* out_b  = (const float*)d_in[9];
    float* out = (float*)d_out;

    const size_t ND4 = (size_t)NN * DD * 4;   // 25,600,000 B
    char* ws = (char*)d_ws;
    float* B0  = (float*)(ws);                 // features / scatter dest
    float* B1  = (float*)(ws + ND4);           // gemm out / scatter src
    float* dis = (float*)(ws + 2 * ND4);
    int*   deg = (int*)  (ws + 2 * ND4 + 256 * 1024);
    float* cs  = (float*)(ws + 2 * ND4 + 512 * 1024);
    float* css = cs + DD;
    // total ws use: 2*25.6MB + ~0.5MB ≈ 51.7MB

    const int gemm_grid = (NN + 63) / 64;     // 782

    hipMemsetAsync(deg, 0, NN * sizeof(int), stream);
    k_deg<<<(EE + 255) / 256, 256, 0, stream>>>(ei, deg);
    k_dis<<<(NN + 255) / 256, 256, 0, stream>>>(deg, dis);

    for (int l = 0; l < 3; ++l) {
        const float* IN = (l == 0) ? x : B0;
        // B1 = (IN @ W) * dis[row]
        k_gemm<0><<<gemm_grid, 256, 0, stream>>>(IN, conv_w + l * DD * DD, nullptr, dis, B1);
        // B0 = scatter-aggregate of B1
        hipMemsetAsync(B0, 0, ND4, stream);
        hipMemsetAsync(cs, 0, 2 * DD * sizeof(float), stream);
        k_scatter<<<EE / 4, 256, 0, stream>>>(ei, B1, B0);
        if (l < 2) k_finalize<0><<<(NN + 127) / 128, 128, 0, stream>>>(B0, B1, dis, conv_b + l * DD, cs, css);
        else       k_finalize<1><<<(NN + 127) / 128, 128, 0, stream>>>(B0, B1, dis, conv_b + l * DD, cs, css);
        int g = (l < 2) ? l : 1;
        k_norm<<<(NN * DD + 255) / 256, 256, 0, stream>>>(B0, cs, css, bn_g + g * DD, bn_b + g * DD, (l < 2) ? 1 : 0);
    }

    k_gemm<1><<<gemm_grid, 256, 0, stream>>>(B0, mlp_w, mlp_b, nullptr, B1);
    k_gemm<1><<<gemm_grid, 256, 0, stream>>>(B1, mlp_w + DD * DD, mlp_b + DD, nullptr, B0);
    k_head<<<(NN + 3) / 4, 256, 0, stream>>>(B0, out_w, out_b, out);
}

// Round 4
// 1274.882 us; speedup vs baseline: 1.9409x; 1.9409x over previous
//
#include <hip/hip_runtime.h>
#include <hip/hip_bf16.h>

#define NN 50000
#define EE 800000
#define DD 128

// ---------------- degree (guarded) ----------------
__global__ void k_deg(const int* __restrict__ ei, int* __restrict__ deg) {
    int e = blockIdx.x * 256 + threadIdx.x;
    if (e < EE) {
        int d = ei[EE + e];                       // dst row
        if (d >= 0 && d < NN) atomicAdd(&deg[d], 1);
    }
}

__global__ void k_dis(const int* __restrict__ deg, float* __restrict__ dis) {
    int i = blockIdx.x * 256 + threadIdx.x;
    if (i < NN) dis[i] = rsqrtf((float)deg[i] + 1.0f);  // +1 self loop; always >0
}

// ---------------- CSR build: block scan of deg -> rowptr ----------------
__global__ void k_scan_block(const int* __restrict__ deg, int* __restrict__ scanned,
                             int* __restrict__ blocksum) {
    __shared__ int lds[256];
    int t = threadIdx.x;
    int i = blockIdx.x * 256 + t;
    int v = (i < NN) ? deg[i] : 0;
    lds[t] = v;
    __syncthreads();
    for (int off = 1; off < 256; off <<= 1) {
        int add = (t >= off) ? lds[t - off] : 0;
        __syncthreads();
        lds[t] += add;
        __syncthreads();
    }
    if (i < NN) scanned[i] = lds[t];              // inclusive within block
    if (t == 255) blocksum[blockIdx.x] = lds[255];
}

__global__ void k_scan_top(const int* __restrict__ blocksum, int* __restrict__ blockoff,
                           int* __restrict__ rowptr_end, int nb) {
    __shared__ int lds[256];
    int t = threadIdx.x;
    int v = (t < nb) ? blocksum[t] : 0;
    lds[t] = v;
    __syncthreads();
    for (int off = 1; off < 256; off <<= 1) {
        int add = (t >= off) ? lds[t - off] : 0;
        __syncthreads();
        lds[t] += add;
        __syncthreads();
    }
    if (t < nb) blockoff[t] = lds[t] - v;         // exclusive
    if (t == nb - 1) *rowptr_end = lds[t];        // total valid edges -> rowptr[NN]
}

// scanned aliases cursor: read then overwrite same index (safe per-thread)
__global__ void k_scan_final(const int* __restrict__ deg, const int* __restrict__ scanned,
                             const int* __restrict__ blockoff,
                             int* __restrict__ rowptr, int* __restrict__ cursor) {
    int i = blockIdx.x * 256 + threadIdx.x;
    if (i < NN) {
        int v = scanned[i] - deg[i] + blockoff[blockIdx.x];  // global exclusive
        rowptr[i] = v;
        cursor[i] = v;
    }
}

__global__ void k_fill(const int* __restrict__ ei, int* __restrict__ cursor,
                       int* __restrict__ csr) {
    int e = blockIdx.x * 256 + threadIdx.x;
    if (e < EE) {
        int s = ei[e];
        int d = ei[EE + e];
        if ((unsigned)s < (unsigned)NN && (unsigned)d < (unsigned)NN) {
            int pos = atomicAdd(&cursor[d], 1);
            csr[pos] = s;
        }
    }
}

// ---------------- GEMM: OUT = IN @ W (+epilogue) ----------------
// MODE 0: OUT[r][:] = (IN@W)[r][:] * dis[r]          (conv pre-aggregation)
// MODE 1: OUT = relu(IN@W + bias)                    (mlp layers)
template<int MODE>
__global__ __launch_bounds__(256) void k_gemm(const float* __restrict__ IN,
                                              const float* __restrict__ Wg,
                                              const float* __restrict__ bias,
                                              const float* __restrict__ dis,
                                              float* __restrict__ OUT) {
    __shared__ float Alds[64][68];
    __shared__ float Wlds[64][128];
    const int tid = threadIdx.x;
    const int tx = tid & 15;
    const int ty = tid >> 4;
    const int row0 = blockIdx.x * 64;

    float acc[4][8];
#pragma unroll
    for (int i = 0; i < 4; ++i)
#pragma unroll
        for (int j = 0; j < 8; ++j) acc[i][j] = 0.f;

    for (int kc = 0; kc < 2; ++kc) {
#pragma unroll
        for (int it = 0; it < 4; ++it) {
            int idx = it * 1024 + tid * 4;
            int r = idx >> 6, k = idx & 63;
            int gr = row0 + r;
            float4 v = make_float4(0.f, 0.f, 0.f, 0.f);
            if (gr < NN) v = *(const float4*)&IN[gr * DD + kc * 64 + k];
            *(float4*)&Alds[r][k] = v;
        }
#pragma unroll
        for (int it = 0; it < 8; ++it) {
            int idx = it * 1024 + tid * 4;
            int k = idx >> 7, c = idx & 127;
            *(float4*)&Wlds[k][c] = *(const float4*)&Wg[(kc * 64 + k) * DD + c];
        }
        __syncthreads();

#pragma unroll 8
        for (int k = 0; k < 64; ++k) {
            float a0 = Alds[ty * 4 + 0][k];
            float a1 = Alds[ty * 4 + 1][k];
            float a2 = Alds[ty * 4 + 2][k];
            float a3 = Alds[ty * 4 + 3][k];
            float4 w0 = *(float4*)&Wlds[k][tx * 8];
            float4 w1 = *(float4*)&Wlds[k][tx * 8 + 4];
            float w[8] = {w0.x, w0.y, w0.z, w0.w, w1.x, w1.y, w1.z, w1.w};
#pragma unroll
            for (int j = 0; j < 8; ++j) {
                acc[0][j] = fmaf(a0, w[j], acc[0][j]);
                acc[1][j] = fmaf(a1, w[j], acc[1][j]);
                acc[2][j] = fmaf(a2, w[j], acc[2][j]);
                acc[3][j] = fmaf(a3, w[j], acc[3][j]);
            }
        }
        __syncthreads();
    }

    float bcol[8];
    if (MODE == 1) {
#pragma unroll
        for (int j = 0; j < 8; ++j) bcol[j] = bias[tx * 8 + j];
    }
#pragma unroll
    for (int i = 0; i < 4; ++i) {
        int r = row0 + ty * 4 + i;
        if (r >= NN) break;
        float scale = (MODE == 0) ? dis[r] : 1.f;
        float o[8];
#pragma unroll
        for (int j = 0; j < 8; ++j) {
            float v = acc[i][j];
            if (MODE == 0) v *= scale;
            else           v = fmaxf(v + bcol[j], 0.f);
            o[j] = v;
        }
        *(float4*)&OUT[r * DD + tx * 8]     = make_float4(o[0], o[1], o[2], o[3]);
        *(float4*)&OUT[r * DD + tx * 8 + 4] = make_float4(o[4], o[5], o[6], o[7]);
    }
}

// ---------------- fused gather + finalize + col stats ----------------
// OUT[r] = relu?( dis[r] * (HS[r] + sum_{s in N(r)} HS[s]) + bias )
// one wave per row (lane -> 2 columns); grid-stride over row groups;
// per-thread register stats, 4 atomics per thread at kernel end.
template<int RELU>
__global__ __launch_bounds__(256) void k_gather(const int* __restrict__ rowptr,
                                                const int* __restrict__ csr,
                                                const float* __restrict__ HS,
                                                const float* __restrict__ dis,
                                                const float* __restrict__ bias,
                                                float* __restrict__ OUT,
                                                float* __restrict__ colsum,
                                                float* __restrict__ colsumsq) {
    const int lane = threadIdx.x & 63;
    const int wid = threadIdx.x >> 6;
    float2 b = ((const float2*)bias)[lane];
    float sx = 0.f, sqx = 0.f, sy = 0.f, sqy = 0.f;

    const int ngroups = (NN + 3) / 4;
    for (int rg = blockIdx.x; rg < ngroups; rg += gridDim.x) {
        int r = rg * 4 + wid;
        if (r < NN) {
            int beg = rowptr[r], end = rowptr[r + 1];
            float2 acc = ((const float2*)(HS + (size_t)r * DD))[lane];   // self loop
            for (int j = beg; j < end; ++j) {
                int s = csr[j];                                          // wave-uniform -> s_load
                float2 v = ((const float2*)(HS + (size_t)s * DD))[lane];
                acc.x += v.x;
                acc.y += v.y;
            }
            float dr = dis[r];
            float vx = fmaf(dr, acc.x, b.x);
            float vy = fmaf(dr, acc.y, b.y);
            if (RELU) { vx = fmaxf(vx, 0.f); vy = fmaxf(vy, 0.f); }
            ((float2*)(OUT + (size_t)r * DD))[lane] = make_float2(vx, vy);
            sx += vx; sqx += vx * vx;
            sy += vy; sqy += vy * vy;
        }
    }
    atomicAdd(&colsum[2 * lane],     sx);
    atomicAdd(&colsum[2 * lane + 1], sy);
    atomicAdd(&colsumsq[2 * lane],     sqx);
    atomicAdd(&colsumsq[2 * lane + 1], sqy);
}

// ---------------- BN apply in-place (+opt relu) ----------------
__global__ __launch_bounds__(256) void k_norm(float* __restrict__ Y,
                                              const float* __restrict__ colsum,
                                              const float* __restrict__ colsumsq,
                                              const float* __restrict__ gamma,
                                              const float* __restrict__ beta,
                                              int relu) {
    int i = blockIdx.x * 256 + threadIdx.x;
    if (i >= NN * DD) return;
    int d = i & (DD - 1);
    const float invn = 1.f / (float)NN;
    float mean = colsum[d] * invn;
    float var = colsumsq[d] * invn - mean * mean;
    float v = (Y[i] - mean) * rsqrtf(fmaxf(var, 0.f) + 1e-5f) * gamma[d] + beta[d];
    if (relu) v = fmaxf(v, 0.f);
    Y[i] = v;
}

// ---------------- head: out = sigmoid(H @ out_w + out_b) ----------------
__global__ __launch_bounds__(256) void k_head(const float* __restrict__ H,
                                              const float* __restrict__ ow,
                                              const float* __restrict__ ob,
                                              float* __restrict__ out) {
    int r = blockIdx.x * 4 + (threadIdx.x >> 6);
    if (r >= NN) return;
    int lane = threadIdx.x & 63;
    float2 h = ((const float2*)(H + (size_t)r * DD))[lane];
    float sum = h.x * ow[lane * 2] + h.y * ow[lane * 2 + 1];
#pragma unroll
    for (int off = 32; off > 0; off >>= 1) sum += __shfl_down(sum, off);
    if (lane == 0) {
        float z = sum + ob[0];
        out[r] = 1.f / (1.f + expf(-z));
    }
}

extern "C" void kernel_launch(void* const* d_in, const int* in_sizes, int n_in,
                              void* d_out, int out_size, void* d_ws, size_t ws_size,
                              hipStream_t stream) {
    const float* x      = (const float*)d_in[0];
    const int*   ei     = (const int*)d_in[1];
    const float* conv_w = (const float*)d_in[2];
    const float* conv_b = (const float*)d_in[3];
    const float* bn_g   = (const float*)d_in[4];
    const float* bn_b   = (const float*)d_in[5];
    const float* mlp_w  = (const float*)d_in[6];
    const float* mlp_b  = (const float*)d_in[7];
    const float* out_w  = (const float*)d_in[8];
    const float* out_b  = (const float*)d_in[9];
    float* out = (float*)d_out;

    const size_t ND4 = (size_t)NN * DD * 4;   // 25,600,000 B
    char* ws = (char*)d_ws;
    size_t off = 0;
    float* B0     = (float*)(ws + off); off += ND4;
    float* B1     = (float*)(ws + off); off += ND4;
    float* dis    = (float*)(ws + off); off += 204800;           // NN*4 rounded
    int*   deg    = (int*)  (ws + off); off += 204800;
    int*   rowptr = (int*)  (ws + off); off += 204804 + 60;      // NN+1, pad to align
    int*   cursor = (int*)  (ws + off); off += 204800;           // also scan scratch
    int*   bsum   = (int*)  (ws + off); off += 1024;
    int*   boff   = (int*)  (ws + off); off += 1024;
    float* cs     = (float*)(ws + off); off += 512;
    float* css    = (float*)(ws + off); off += 512;
    int*   csr    = (int*)  (ws + off); off += (size_t)EE * 4;
    // total ≈ 55.4 MB

    const int gemm_grid = (NN + 63) / 64;     // 782
    const int nscan = (NN + 255) / 256;       // 196

    // ---- CSR build (graph static within launch) ----
    hipMemsetAsync(deg, 0, NN * sizeof(int), stream);
    k_deg<<<(EE + 255) / 256, 256, 0, stream>>>(ei, deg);
    k_dis<<<(NN + 255) / 256, 256, 0, stream>>>(deg, dis);
    k_scan_block<<<nscan, 256, 0, stream>>>(deg, cursor, bsum);
    k_scan_top<<<1, 256, 0, stream>>>(bsum, boff, rowptr + NN, nscan);
    k_scan_final<<<nscan, 256, 0, stream>>>(deg, cursor, boff, rowptr, cursor);
    k_fill<<<(EE + 255) / 256, 256, 0, stream>>>(ei, cursor, csr);

    for (int l = 0; l < 3; ++l) {
        const float* IN = (l == 0) ? x : B0;
        k_gemm<0><<<gemm_grid, 256, 0, stream>>>(IN, conv_w + l * DD * DD, nullptr, dis, B1);
        hipMemsetAsync(cs, 0, 2 * DD * sizeof(float), stream);
        if (l < 2) k_gather<0><<<512, 256, 0, stream>>>(rowptr, csr, B1, dis, conv_b + l * DD, B0, cs, css);
        else       k_gather<1><<<512, 256, 0, stream>>>(rowptr, csr, B1, dis, conv_b + l * DD, B0, cs, css);
        int g = (l < 2) ? l : 1;
        k_norm<<<(NN * DD + 255) / 256, 256, 0, stream>>>(B0, cs, css, bn_g + g * DD, bn_b + g * DD, (l < 2) ? 1 : 0);
    }

    k_gemm<1><<<gemm_grid, 256, 0, stream>>>(B0, mlp_w, mlp_b, nullptr, B1);
    k_gemm<1><<<gemm_grid, 256, 0, stream>>>(B1, mlp_w + DD * DD, mlp_b + DD, nullptr, B0);
    k_head<<<(NN + 3) / 4, 256, 0, stream>>>(B0, out_w, out_b, out);
}

// Round 5
// 826.184 us; speedup vs baseline: 2.9951x; 1.5431x over previous
//
#include <hip/hip_runtime.h>
#include <hip/hip_bf16.h>

#define NN 50000
#define EE 800000
#define DD 128

// ---------------- degree (guarded) ----------------
__global__ void k_deg(const int* __restrict__ ei, int* __restrict__ deg) {
    int e = blockIdx.x * 256 + threadIdx.x;
    if (e < EE) {
        int d = ei[EE + e];                       // dst row
        if (d >= 0 && d < NN) atomicAdd(&deg[d], 1);
    }
}

__global__ void k_dis(const int* __restrict__ deg, float* __restrict__ dis) {
    int i = blockIdx.x * 256 + threadIdx.x;
    if (i < NN) dis[i] = rsqrtf((float)deg[i] + 1.0f);  // +1 self loop; always >0
}

// ---------------- CSR build: block scan of deg -> rowptr ----------------
__global__ void k_scan_block(const int* __restrict__ deg, int* __restrict__ scanned,
                             int* __restrict__ blocksum) {
    __shared__ int lds[256];
    int t = threadIdx.x;
    int i = blockIdx.x * 256 + t;
    int v = (i < NN) ? deg[i] : 0;
    lds[t] = v;
    __syncthreads();
    for (int off = 1; off < 256; off <<= 1) {
        int add = (t >= off) ? lds[t - off] : 0;
        __syncthreads();
        lds[t] += add;
        __syncthreads();
    }
    if (i < NN) scanned[i] = lds[t];              // inclusive within block
    if (t == 255) blocksum[blockIdx.x] = lds[255];
}

__global__ void k_scan_top(const int* __restrict__ blocksum, int* __restrict__ blockoff,
                           int* __restrict__ rowptr_end, int nb) {
    __shared__ int lds[256];
    int t = threadIdx.x;
    int v = (t < nb) ? blocksum[t] : 0;
    lds[t] = v;
    __syncthreads();
    for (int off = 1; off < 256; off <<= 1) {
        int add = (t >= off) ? lds[t - off] : 0;
        __syncthreads();
        lds[t] += add;
        __syncthreads();
    }
    if (t < nb) blockoff[t] = lds[t] - v;         // exclusive
    if (t == nb - 1) *rowptr_end = lds[t];        // total valid edges -> rowptr[NN]
}

__global__ void k_scan_final(const int* __restrict__ deg, const int* __restrict__ scanned,
                             const int* __restrict__ blockoff,
                             int* __restrict__ rowptr, int* __restrict__ cursor) {
    int i = blockIdx.x * 256 + threadIdx.x;
    if (i < NN) {
        int v = scanned[i] - deg[i] + blockoff[blockIdx.x];  // global exclusive
        rowptr[i] = v;
        cursor[i] = v;
    }
}

__global__ void k_fill(const int* __restrict__ ei, int* __restrict__ cursor,
                       int* __restrict__ csr) {
    int e = blockIdx.x * 256 + threadIdx.x;
    if (e < EE) {
        int s = ei[e];
        int d = ei[EE + e];
        if ((unsigned)s < (unsigned)NN && (unsigned)d < (unsigned)NN) {
            int pos = atomicAdd(&cursor[d], 1);
            csr[pos] = s;
        }
    }
}

// ---------------- BN prep: scale/shift from col stats ----------------
__global__ void k_bnprep(const float* __restrict__ cs, const float* __restrict__ css,
                         const float* __restrict__ gamma, const float* __restrict__ beta,
                         float* __restrict__ bnsc, float* __restrict__ bnsh) {
    int d = threadIdx.x;
    const float invn = 1.f / (float)NN;
    float mean = cs[d] * invn;
    float var = css[d] * invn - mean * mean;
    float sc = gamma[d] * rsqrtf(fmaxf(var, 0.f) + 1e-5f);
    bnsc[d] = sc;
    bnsh[d] = beta[d] - mean * sc;
}

// ---------------- GEMM: OUT = pro(IN) @ W (+epilogue) ----------------
// PRO: 0=none, 1=BN+relu applied to A while staging, 2=BN only
// EPI: 0=scale rows by dis[r], 1=+bias then relu
template<int PRO, int EPI>
__global__ __launch_bounds__(256) void k_gemm(const float* __restrict__ IN,
                                              const float* __restrict__ Wg,
                                              const float* __restrict__ bias,
                                              const float* __restrict__ dis,
                                              const float* __restrict__ bnsc,
                                              const float* __restrict__ bnsh,
                                              float* __restrict__ OUT) {
    __shared__ float Alds[64][68];
    __shared__ float Wlds[64][128];
    const int tid = threadIdx.x;
    const int tx = tid & 15;
    const int ty = tid >> 4;
    const int row0 = blockIdx.x * 64;

    float acc[4][8];
#pragma unroll
    for (int i = 0; i < 4; ++i)
#pragma unroll
        for (int j = 0; j < 8; ++j) acc[i][j] = 0.f;

    for (int kc = 0; kc < 2; ++kc) {
#pragma unroll
        for (int it = 0; it < 4; ++it) {
            int idx = it * 1024 + tid * 4;
            int r = idx >> 6, k = idx & 63;
            int gr = row0 + r;
            float4 v = make_float4(0.f, 0.f, 0.f, 0.f);
            if (gr < NN) v = *(const float4*)&IN[gr * DD + kc * 64 + k];
            if (PRO) {
                float4 sc = *(const float4*)&bnsc[kc * 64 + k];
                float4 sh = *(const float4*)&bnsh[kc * 64 + k];
                v.x = fmaf(v.x, sc.x, sh.x);
                v.y = fmaf(v.y, sc.y, sh.y);
                v.z = fmaf(v.z, sc.z, sh.z);
                v.w = fmaf(v.w, sc.w, sh.w);
                if (PRO == 1) {
                    v.x = fmaxf(v.x, 0.f); v.y = fmaxf(v.y, 0.f);
                    v.z = fmaxf(v.z, 0.f); v.w = fmaxf(v.w, 0.f);
                }
            }
            *(float4*)&Alds[r][k] = v;
        }
#pragma unroll
        for (int it = 0; it < 8; ++it) {
            int idx = it * 1024 + tid * 4;
            int k = idx >> 7, c = idx & 127;
            *(float4*)&Wlds[k][c] = *(const float4*)&Wg[(kc * 64 + k) * DD + c];
        }
        __syncthreads();

#pragma unroll 8
        for (int k = 0; k < 64; ++k) {
            float a0 = Alds[ty * 4 + 0][k];
            float a1 = Alds[ty * 4 + 1][k];
            float a2 = Alds[ty * 4 + 2][k];
            float a3 = Alds[ty * 4 + 3][k];
            float4 w0 = *(float4*)&Wlds[k][tx * 8];
            float4 w1 = *(float4*)&Wlds[k][tx * 8 + 4];
            float w[8] = {w0.x, w0.y, w0.z, w0.w, w1.x, w1.y, w1.z, w1.w};
#pragma unroll
            for (int j = 0; j < 8; ++j) {
                acc[0][j] = fmaf(a0, w[j], acc[0][j]);
                acc[1][j] = fmaf(a1, w[j], acc[1][j]);
                acc[2][j] = fmaf(a2, w[j], acc[2][j]);
                acc[3][j] = fmaf(a3, w[j], acc[3][j]);
            }
        }
        __syncthreads();
    }

    float bcol[8];
    if (EPI == 1) {
#pragma unroll
        for (int j = 0; j < 8; ++j) bcol[j] = bias[tx * 8 + j];
    }
#pragma unroll
    for (int i = 0; i < 4; ++i) {
        int r = row0 + ty * 4 + i;
        if (r >= NN) break;
        float scale = (EPI == 0) ? dis[r] : 1.f;
        float o[8];
#pragma unroll
        for (int j = 0; j < 8; ++j) {
            float v = acc[i][j];
            if (EPI == 0) v *= scale;
            else          v = fmaxf(v + bcol[j], 0.f);
            o[j] = v;
        }
        *(float4*)&OUT[r * DD + tx * 8]     = make_float4(o[0], o[1], o[2], o[3]);
        *(float4*)&OUT[r * DD + tx * 8 + 4] = make_float4(o[4], o[5], o[6], o[7]);
    }
}

// ---------------- fused gather + finalize + col stats ----------------
// OUT[r] = relu?( dis[r] * (HS[r] + sum_{s in N(r)} HS[s]) + bias ), col stats -> atomics
template<int RELU>
__global__ __launch_bounds__(256) void k_gather(const int* __restrict__ rowptr,
                                                const int* __restrict__ csr,
                                                const float* __restrict__ HS,
                                                const float* __restrict__ dis,
                                                const float* __restrict__ bias,
                                                float* __restrict__ OUT,
                                                float* __restrict__ colsum,
                                                float* __restrict__ colsumsq) {
    const int lane = threadIdx.x & 63;
    const int wid = threadIdx.x >> 6;
    float2 b = ((const float2*)bias)[lane];
    float sx = 0.f, sqx = 0.f, sy = 0.f, sqy = 0.f;

    const int ngroups = (NN + 3) / 4;
    for (int rg = blockIdx.x; rg < ngroups; rg += gridDim.x) {
        int r = rg * 4 + wid;
        if (r < NN) {
            int beg = rowptr[r], end = rowptr[r + 1];
            float2 acc = ((const float2*)(HS + (size_t)r * DD))[lane];   // self loop
            int j = beg;
            for (; j + 3 < end; j += 4) {
                int s0 = csr[j], s1 = csr[j + 1], s2 = csr[j + 2], s3 = csr[j + 3];
                float2 v0 = ((const float2*)(HS + (size_t)s0 * DD))[lane];
                float2 v1 = ((const float2*)(HS + (size_t)s1 * DD))[lane];
                float2 v2 = ((const float2*)(HS + (size_t)s2 * DD))[lane];
                float2 v3 = ((const float2*)(HS + (size_t)s3 * DD))[lane];
                acc.x += (v0.x + v1.x) + (v2.x + v3.x);
                acc.y += (v0.y + v1.y) + (v2.y + v3.y);
            }
            for (; j < end; ++j) {
                int s = csr[j];
                float2 v = ((const float2*)(HS + (size_t)s * DD))[lane];
                acc.x += v.x;
                acc.y += v.y;
            }
            float dr = dis[r];
            float vx = fmaf(dr, acc.x, b.x);
            float vy = fmaf(dr, acc.y, b.y);
            if (RELU) { vx = fmaxf(vx, 0.f); vy = fmaxf(vy, 0.f); }
            ((float2*)(OUT + (size_t)r * DD))[lane] = make_float2(vx, vy);
            sx += vx; sqx += vx * vx;
            sy += vy; sqy += vy * vy;
        }
    }

    // block-level stats reduction: 4 waves -> wave 0 -> 256 atomics/block
    __shared__ float4 red[4][64];
    red[wid][lane] = make_float4(sx, sy, sqx, sqy);
    __syncthreads();
    if (wid == 0) {
        float4 a = red[0][lane], c = red[1][lane], d = red[2][lane], e = red[3][lane];
        float rx  = (a.x + c.x) + (d.x + e.x);
        float ry  = (a.y + c.y) + (d.y + e.y);
        float rqx = (a.z + c.z) + (d.z + e.z);
        float rqy = (a.w + c.w) + (d.w + e.w);
        atomicAdd(&colsum[2 * lane],       rx);
        atomicAdd(&colsum[2 * lane + 1],   ry);
        atomicAdd(&colsumsq[2 * lane],     rqx);
        atomicAdd(&colsumsq[2 * lane + 1], rqy);
    }
}

// ---------------- head: out = sigmoid(H @ out_w + out_b) ----------------
__global__ __launch_bounds__(256) void k_head(const float* __restrict__ H,
                                              const float* __restrict__ ow,
                                              const float* __restrict__ ob,
                                              float* __restrict__ out) {
    int r = blockIdx.x * 4 + (threadIdx.x >> 6);
    if (r >= NN) return;
    int lane = threadIdx.x & 63;
    float2 h = ((const float2*)(H + (size_t)r * DD))[lane];
    float sum = h.x * ow[lane * 2] + h.y * ow[lane * 2 + 1];
#pragma unroll
    for (int off = 32; off > 0; off >>= 1) sum += __shfl_down(sum, off);
    if (lane == 0) {
        float z = sum + ob[0];
        out[r] = 1.f / (1.f + expf(-z));
    }
}

extern "C" void kernel_launch(void* const* d_in, const int* in_sizes, int n_in,
                              void* d_out, int out_size, void* d_ws, size_t ws_size,
                              hipStream_t stream) {
    const float* x      = (const float*)d_in[0];
    const int*   ei     = (const int*)d_in[1];
    const float* conv_w = (const float*)d_in[2];
    const float* conv_b = (const float*)d_in[3];
    const float* bn_g   = (const float*)d_in[4];
    const float* bn_b   = (const float*)d_in[5];
    const float* mlp_w  = (const float*)d_in[6];
    const float* mlp_b  = (const float*)d_in[7];
    const float* out_w  = (const float*)d_in[8];
    const float* out_b  = (const float*)d_in[9];
    float* out = (float*)d_out;

    const size_t ND4 = (size_t)NN * DD * 4;   // 25,600,000 B
    char* ws = (char*)d_ws;
    size_t off = 0;
    float* B0     = (float*)(ws + off); off += ND4;
    float* B1     = (float*)(ws + off); off += ND4;
    float* dis    = (float*)(ws + off); off += 204800;           // NN*4 rounded
    int*   deg    = (int*)  (ws + off); off += 204800;
    int*   rowptr = (int*)  (ws + off); off += 204804 + 60;      // NN+1, pad to align
    int*   cursor = (int*)  (ws + off); off += 204800;           // also scan scratch
    int*   bsum   = (int*)  (ws + off); off += 1024;
    int*   boff   = (int*)  (ws + off); off += 1024;
    float* cs     = (float*)(ws + off); off += 512;
    float* css    = (float*)(ws + off); off += 512;
    float* bnsc   = (float*)(ws + off); off += 512;
    float* bnsh   = (float*)(ws + off); off += 512;
    int*   csr    = (int*)  (ws + off); off += (size_t)EE * 4;
    // total ≈ 55.4 MB

    const int gemm_grid = (NN + 63) / 64;     // 782
    const int nscan = (NN + 255) / 256;       // 196
    const int gather_grid = 2048;             // 8192 waves = full occupancy

    // ---- CSR build (graph static within launch) ----
    hipMemsetAsync(deg, 0, NN * sizeof(int), stream);
    k_deg<<<(EE + 255) / 256, 256, 0, stream>>>(ei, deg);
    k_dis<<<(NN + 255) / 256, 256, 0, stream>>>(deg, dis);
    k_scan_block<<<nscan, 256, 0, stream>>>(deg, cursor, bsum);
    k_scan_top<<<1, 256, 0, stream>>>(bsum, boff, rowptr + NN, nscan);
    k_scan_final<<<nscan, 256, 0, stream>>>(deg, cursor, boff, rowptr, cursor);
    k_fill<<<(EE + 255) / 256, 256, 0, stream>>>(ei, cursor, csr);

    // ---- layer 0: conv(x) ----
    k_gemm<0, 0><<<gemm_grid, 256, 0, stream>>>(x, conv_w, nullptr, dis, nullptr, nullptr, B1);
    hipMemsetAsync(cs, 0, 2 * DD * sizeof(float), stream);
    k_gather<0><<<gather_grid, 256, 0, stream>>>(rowptr, csr, B1, dis, conv_b, B0, cs, css);
    k_bnprep<<<1, 128, 0, stream>>>(cs, css, bn_g, bn_b, bnsc, bnsh);

    // ---- layer 1: conv(bn_relu(B0)) ----
    k_gemm<1, 0><<<gemm_grid, 256, 0, stream>>>(B0, conv_w + DD * DD, nullptr, dis, bnsc, bnsh, B1);
    hipMemsetAsync(cs, 0, 2 * DD * sizeof(float), stream);
    k_gather<0><<<gather_grid, 256, 0, stream>>>(rowptr, csr, B1, dis, conv_b + DD, B0, cs, css);
    k_bnprep<<<1, 128, 0, stream>>>(cs, css, bn_g + DD, bn_b + DD, bnsc, bnsh);

    // ---- layer 2: conv(bn_relu(B0)), relu'd gather, then BN (bns[-1]) ----
    k_gemm<1, 0><<<gemm_grid, 256, 0, stream>>>(B0, conv_w + 2 * DD * DD, nullptr, dis, bnsc, bnsh, B1);
    hipMemsetAsync(cs, 0, 2 * DD * sizeof(float), stream);
    k_gather<1><<<gather_grid, 256, 0, stream>>>(rowptr, csr, B1, dis, conv_b + 2 * DD, B0, cs, css);
    k_bnprep<<<1, 128, 0, stream>>>(cs, css, bn_g + DD, bn_b + DD, bnsc, bnsh);

    // ---- MLP head ----
    k_gemm<2, 1><<<gemm_grid, 256, 0, stream>>>(B0, mlp_w, mlp_b, dis, bnsc, bnsh, B1);
    k_gemm<0, 1><<<gemm_grid, 256, 0, stream>>>(B1, mlp_w + DD * DD, mlp_b + DD, dis, nullptr, nullptr, B0);
    k_head<<<(NN + 3) / 4, 256, 0, stream>>>(B0, out_w, out_b, out);
}